// Round 16
// baseline (322.734 us; speedup 1.0000x reference)
//
#include <hip/hip_runtime.h>
#include <math.h>

#define NNODES 50000
#define NEDGES 800000
#define NTOT   850000   // edges + self-loops
#define NHEAD  8
#define HDIM   32
#define HHD    256      // NHEAD*HDIM
#define NCLS   40
#define NEG_SLOPE 0.2f

typedef _Float16 half4 __attribute__((ext_vector_type(4)));
typedef _Float16 half8 __attribute__((ext_vector_type(8)));
typedef float f32x16 __attribute__((ext_vector_type(16)));
typedef unsigned short u16;

// ---------------- CSR build ----------------
// counts is memset to 0 on the stream; scan1 adds +1 per node (self-loop).

__global__ void k_count(const int* __restrict__ ei, int* __restrict__ counts) {
    int i = blockIdx.x * 256 + threadIdx.x;
    if (i < NEDGES) atomicAdd(&counts[ei[NEDGES + i]], 1);  // dst row
}

__global__ __launch_bounds__(256) void k_scan1(const int* __restrict__ counts,
                                               int* __restrict__ partial,
                                               int* __restrict__ bsums) {
    __shared__ int lds[256];
    int t = threadIdx.x;
    int i = blockIdx.x * 256 + t;
    int v = (i < NNODES) ? counts[i] + 1 : 0;   // +1 = self-loop
    lds[t] = v;
    __syncthreads();
    for (int off = 1; off < 256; off <<= 1) {
        int add = (t >= off) ? lds[t - off] : 0;
        __syncthreads();
        lds[t] += add;
        __syncthreads();
    }
    if (i < NNODES) partial[i] = lds[t] - v;   // exclusive within block
    if (t == 255) bsums[blockIdx.x] = lds[255];
}

__global__ __launch_bounds__(256) void k_scan2(const int* __restrict__ bsums,
                                               int* __restrict__ boff, int nb) {
    __shared__ int lds[256];
    int t = threadIdx.x;
    int v = (t < nb) ? bsums[t] : 0;
    lds[t] = v;
    __syncthreads();
    for (int off = 1; off < 256; off <<= 1) {
        int add = (t >= off) ? lds[t - off] : 0;
        __syncthreads();
        lds[t] += add;
        __syncthreads();
    }
    if (t < nb) boff[t] = lds[t] - v;
}

__global__ void k_scan3(int* __restrict__ row_ptr, const int* __restrict__ boff,
                        int* __restrict__ cursor) {
    int i = blockIdx.x * 256 + threadIdx.x;
    if (i < NNODES) {
        int r = row_ptr[i] + boff[blockIdx.x];
        row_ptr[i] = r;
        cursor[i] = r;
    }
    if (i == 0) row_ptr[NNODES] = NTOT;
}

// fused: regular edges + self-loops
__global__ void k_scatter(const int* __restrict__ ei, int* __restrict__ cursor,
                          int* __restrict__ esrc) {
    int i = blockIdx.x * 256 + threadIdx.x;
    if (i < NEDGES) {
        int s = ei[i];
        int d = ei[NEDGES + i];
        int pos = atomicAdd(&cursor[d], 1);
        esrc[pos] = s;
    } else if (i < NTOT) {
        int n = i - NEDGES;
        int pos = atomicAdd(&cursor[n], 1);
        esrc[pos] = n;
    }
}

// ---------------- weight prep: all three weights, MFMA fragment layout -----
// frag f=(fn,fk); lane l holds 8 halves of col n=fn*32+(l&31),
// rows k=fk*16+((l>>5)<<3)+j. 1 KB contiguous per frag.
__global__ void k_prep_all(const float* __restrict__ W1, const float* __restrict__ W2,
                           const float* __restrict__ Wc,
                           _Float16* __restrict__ w1t, _Float16* __restrict__ w2t,
                           _Float16* __restrict__ wct) {
    int gid = blockIdx.x * 256 + threadIdx.x;   // 256 frags x 64 lanes
    if (gid >= 256 * 64) return;
    int frag = gid >> 6, l = gid & 63;
    const float* W; _Float16* Wt; int K, Nc, fkn, fbase;
    if (frag < 64)       { W = W1; Wt = w1t; K = 128; Nc = 256; fkn = 8;  fbase = 0; }
    else if (frag < 192) { W = W2; Wt = w2t; K = 256; Nc = 256; fkn = 16; fbase = 64; }
    else                 { W = Wc; Wt = wct; K = 256; Nc = 40;  fkn = 16; fbase = 192; }
    int f = frag - fbase;
    int fn = f / fkn, fk = f - fn * fkn;
    int n = fn * 32 + (l & 31);
    int k = fk * 16 + ((l >> 5) << 3);
    half8 v;
    #pragma unroll
    for (int j = 0; j < 8; ++j)
        v[j] = (n < Nc) ? (_Float16)W[(size_t)(k + j) * Nc + n] : (_Float16)0.f;
    *reinterpret_cast<half8*>(Wt + ((size_t)f * 64 + l) * 8) = v;
}

// ---------------- MFMA f16 GEMM: one-shot full-K staging, barrier-free loop -
// A-tile (64 x K fp16, <=33 KB) staged entirely into LDS once (1 barrier),
// then all K/16 MFMA steps run with no barriers -> B loads + ds_reads
// pipeline freely. MODE 0: fp16 C via Ct union + alpha epilogue.
// MODE 1: direct fp32 + bias, cols < NCLS.
#define TBM 64
#define TBN 128
#define LDCT 132   // Ct row stride in halves

template <typename AT, int K, int MODE>
__global__ __launch_bounds__(256) void k_mfma_gemm(
    const AT* __restrict__ A,
    const _Float16* __restrict__ Wt,   // fragment-packed
    _Float16* __restrict__ Ch,
    float* __restrict__ Cf,
    const float* __restrict__ bias,
    const float* __restrict__ a_src,   // [8][32] (MODE 0)
    const float* __restrict__ a_dst,
    float* __restrict__ alpha_s,       // [N][8]
    float* __restrict__ alpha_d,
    int M, int ldc)
{
    constexpr bool A_IS_F32 = sizeof(AT) == 4;
    constexpr int APADK = K + 2;   // odd dword row stride -> conflict-free b128
    constexpr int A_ELEMS = TBM * APADK;
    constexpr int CT_ELEMS = (MODE == 0) ? TBM * LDCT : 0;
    constexpr int SMEM_ELEMS = (A_ELEMS > CT_ELEMS) ? A_ELEMS : CT_ELEMS;
    __shared__ _Float16 smem[SMEM_ELEMS];
    int t = threadIdx.x;
    int lane = t & 63;
    int wid = t >> 6;
    int wr = wid >> 1, wc = wid & 1;            // 2x2 wave grid; wave = 32r x 64c
    int rowBase = blockIdx.y * TBM;
    int colBase = blockIdx.x * TBN;

    int arow = t >> 2;                 // 64 rows, 4 threads/row
    int acoff = (t & 3) * (K / 4);     // contiguous K/4-elem run per thread
    bool arow_ok = (rowBase + arow) < M;
    const AT* aptr = A + (size_t)(rowBase + arow) * K + acoff;

    constexpr int FKN = K >> 4;   // frags per n-tile row
    size_t bbase[2];
    #pragma unroll
    for (int ct = 0; ct < 2; ++ct) {
        int fn = blockIdx.x * 4 + wc * 2 + ct;
        bbase[ct] = ((size_t)fn * FKN) * 512 + (size_t)lane * 8;
    }

    f32x16 acc[2];
    #pragma unroll
    for (int j = 0; j < 2; ++j)
        #pragma unroll
        for (int r = 0; r < 16; ++r) acc[j][r] = 0.f;

    // ---- one-shot A staging (K/32 chunks of 8 elems per thread) ----
    #pragma unroll
    for (int c = 0; c < K / 32; ++c) {
        half8 hv;
        if constexpr (A_IS_F32) {
            float4 v0 = {0.f, 0.f, 0.f, 0.f}, v1 = {0.f, 0.f, 0.f, 0.f};
            if (arow_ok) {
                v0 = *reinterpret_cast<const float4*>((const float*)aptr + c * 8);
                v1 = *reinterpret_cast<const float4*>((const float*)aptr + c * 8 + 4);
            }
            hv[0] = (_Float16)v0.x; hv[1] = (_Float16)v0.y;
            hv[2] = (_Float16)v0.z; hv[3] = (_Float16)v0.w;
            hv[4] = (_Float16)v1.x; hv[5] = (_Float16)v1.y;
            hv[6] = (_Float16)v1.z; hv[7] = (_Float16)v1.w;
        } else {
            hv = arow_ok ? *reinterpret_cast<const half8*>((const _Float16*)aptr + c * 8)
                         : half8{0, 0, 0, 0, 0, 0, 0, 0};
        }
        *reinterpret_cast<half8*>(&smem[arow * APADK + acoff + c * 8]) = hv;
    }
    __syncthreads();

    // ---- barrier-free MFMA loop over all K ----
    #pragma unroll
    for (int fk = 0; fk < FKN; ++fk) {
        int kfo = fk * 16 + (lane >> 5) * 8;
        half8 ah = *reinterpret_cast<const half8*>(
            &smem[(wr * 32 + (lane & 31)) * APADK + kfo]);
        #pragma unroll
        for (int ct = 0; ct < 2; ++ct) {
            half8 bh = *reinterpret_cast<const half8*>(
                Wt + bbase[ct] + (size_t)fk * 512);
            acc[ct] = __builtin_amdgcn_mfma_f32_32x32x16_f16(ah, bh, acc[ct], 0, 0, 0);
        }
    }
    __syncthreads();
    // smem (A) dead -> reused as Ct (MODE 0)

    if constexpr (MODE == 0) {
        // acc -> Ct (scalar LDS stores; C-layout transpose)
        #pragma unroll
        for (int ct = 0; ct < 2; ++ct) {
            int lcol = wc * 64 + ct * 32 + (lane & 31);
            #pragma unroll
            for (int r = 0; r < 16; ++r) {
                int lrow = wr * 32 + (r & 3) + 8 * (r >> 2) + 4 * (lane >> 5);
                smem[lrow * LDCT + lcol] = (_Float16)acc[ct][r];
            }
        }
        __syncthreads();
        // vectorized C write: 64 rows x 16 col-chunks (half8) = 4 passes
        #pragma unroll
        for (int pass = 0; pass < 4; ++pass) {
            int idx = t + pass * 256;
            int lrow = idx >> 4;
            int cchunk = (idx & 15) * 8;
            int grow = rowBase + lrow;
            if (grow < M) {
                half8 v = *reinterpret_cast<const half8*>(&smem[lrow * LDCT + cchunk]);
                *reinterpret_cast<half8*>(Ch + (size_t)grow * ldc + colBase + cchunk) = v;
            }
        }
        // alpha epilogue: 64 rows x 4 heads = 256 pairs, 1 per thread
        {
            int lrow = t >> 2, hoff = t & 3;
            int grow = rowBase + lrow;
            if (grow < M) {
                int h = blockIdx.x * 4 + hoff;
                const float* as4 = a_src + h * HDIM;
                const float* ad4 = a_dst + h * HDIM;
                float ss = 0.f, sd = 0.f;
                #pragma unroll
                for (int j = 0; j < HDIM; ++j) {
                    float v = (float)smem[lrow * LDCT + hoff * 32 + j];
                    ss += v * as4[j];
                    sd += v * ad4[j];
                }
                alpha_s[grow * NHEAD + h] = ss;
                alpha_d[grow * NHEAD + h] = sd;
            }
        }
    } else {
        // classifier: direct fp32 + bias, cols < NCLS
        #pragma unroll
        for (int ct = 0; ct < 2; ++ct) {
            int col = colBase + wc * 64 + ct * 32 + (lane & 31);
            #pragma unroll
            for (int r = 0; r < 16; ++r) {
                int row = rowBase + wr * 32 + (r & 3) + 8 * (r >> 2) + 4 * (lane >> 5);
                if (row < M && col < NCLS)
                    Cf[(size_t)row * ldc + col] = acc[ct][r] + bias[col];
            }
        }
    }
}

// ---------------- GAT aggregation: fused single-pass softmax + gather ------
// 2 nodes per wave; lane l in [0,32) covers dims [8l, 8l+8) via one half8.
// No max-subtraction: e is a small-scale dot (|e| << 80), exp cannot overflow.
// Manual 4-way unroll for memory-level parallelism (4 gathers in flight).
__global__ __launch_bounds__(256) void k_agg(const _Float16* __restrict__ xh,
                                             const float* __restrict__ alpha_s,
                                             const float* __restrict__ alpha_d,
                                             const int* __restrict__ row_ptr,
                                             const int* __restrict__ esrc,
                                             const float* __restrict__ bias,
                                             _Float16* __restrict__ out) {
    int wave = blockIdx.x * 4 + (threadIdx.x >> 6);
    int node = wave * 2 + ((threadIdx.x & 63) >> 5);
    if (node >= NNODES) return;
    int l = threadIdx.x & 31;        // dim chunk [8l, 8l+8)
    int h = l >> 2;                  // head of this chunk
    int beg = row_ptr[node], end = row_ptr[node + 1];
    float ad = alpha_d[node * NHEAD + h];
    float acc[8] = {};
    float ssum = 0.f;
    int i = beg;
    for (; i + 3 < end; i += 4) {
        int s0 = esrc[i], s1 = esrc[i + 1], s2 = esrc[i + 2], s3 = esrc[i + 3];
        float e0 = alpha_s[s0 * NHEAD + h] + ad;
        float e1 = alpha_s[s1 * NHEAD + h] + ad;
        float e2 = alpha_s[s2 * NHEAD + h] + ad;
        float e3 = alpha_s[s3 * NHEAD + h] + ad;
        half8 v0 = *reinterpret_cast<const half8*>(xh + (size_t)s0 * HHD + l * 8);
        half8 v1 = *reinterpret_cast<const half8*>(xh + (size_t)s1 * HHD + l * 8);
        half8 v2 = *reinterpret_cast<const half8*>(xh + (size_t)s2 * HHD + l * 8);
        half8 v3 = *reinterpret_cast<const half8*>(xh + (size_t)s3 * HHD + l * 8);
        e0 = (e0 > 0.f) ? e0 : NEG_SLOPE * e0;
        e1 = (e1 > 0.f) ? e1 : NEG_SLOPE * e1;
        e2 = (e2 > 0.f) ? e2 : NEG_SLOPE * e2;
        e3 = (e3 > 0.f) ? e3 : NEG_SLOPE * e3;
        float p0 = __expf(e0), p1 = __expf(e1), p2 = __expf(e2), p3 = __expf(e3);
        ssum += (p0 + p1) + (p2 + p3);
        #pragma unroll
        for (int d = 0; d < 8; ++d)
            acc[d] += p0 * (float)v0[d] + p1 * (float)v1[d] +
                      p2 * (float)v2[d] + p3 * (float)v3[d];
    }
    for (; i < end; ++i) {
        int s0 = esrc[i];
        float e0 = alpha_s[s0 * NHEAD + h] + ad;
        half8 v0 = *reinterpret_cast<const half8*>(xh + (size_t)s0 * HHD + l * 8);
        e0 = (e0 > 0.f) ? e0 : NEG_SLOPE * e0;
        float p0 = __expf(e0);
        ssum += p0;
        #pragma unroll
        for (int d = 0; d < 8; ++d)
            acc[d] += p0 * (float)v0[d];
    }
    float inv = 1.f / ssum;
    float4 b0 = *reinterpret_cast<const float4*>(bias + l * 8);
    float4 b1 = *reinterpret_cast<const float4*>(bias + l * 8 + 4);
    float bb[8] = {b0.x, b0.y, b0.z, b0.w, b1.x, b1.y, b1.z, b1.w};
    half8 r;
    #pragma unroll
    for (int d = 0; d < 8; ++d)
        r[d] = (_Float16)fmaxf(acc[d] * inv + bb[d], 0.f);
    *reinterpret_cast<half8*>(out + (size_t)node * HHD + l * 8) = r;
}

// ---------------- launch ----------------

extern "C" void kernel_launch(void* const* d_in, const int* in_sizes, int n_in,
                              void* d_out, int out_size, void* d_ws, size_t ws_size,
                              hipStream_t stream) {
    const float* x   = (const float*)d_in[0];
    const int*   ei  = (const int*)  d_in[1];
    const float* W1  = (const float*)d_in[2];
    const float* a1s = (const float*)d_in[3];
    const float* a1d = (const float*)d_in[4];
    const float* b1  = (const float*)d_in[5];
    const float* W2  = (const float*)d_in[6];
    const float* a2s = (const float*)d_in[7];
    const float* a2d = (const float*)d_in[8];
    const float* b2  = (const float*)d_in[9];
    const float* Wc  = (const float*)d_in[10];
    const float* bc  = (const float*)d_in[11];
    float* out = (float*)d_out;

    char* ws = (char*)d_ws;
    size_t off = 0;
    auto alloc = [&](size_t bytes) -> void* {
        void* p = ws + off;
        off += (bytes + 255) & ~(size_t)255;
        return p;
    };
    _Float16* xh_h   = (_Float16*)alloc((size_t)NNODES * HHD * 2);
    _Float16* hbuf_h = (_Float16*)alloc((size_t)NNODES * HHD * 2);
    float* as_   = (float*)alloc((size_t)NNODES * NHEAD * 4);
    float* ad_   = (float*)alloc((size_t)NNODES * NHEAD * 4);
    int* counts  = (int*)alloc((size_t)NNODES * 4);
    int* row_ptr = (int*)alloc((size_t)(NNODES + 1) * 4);
    int* cursor  = (int*)alloc((size_t)NNODES * 4);
    int* esrc    = (int*)alloc((size_t)NTOT * 4);
    int* bsums   = (int*)alloc(256 * 4);
    int* boff    = (int*)alloc(256 * 4);
    _Float16* w1t = (_Float16*)alloc((size_t)64 * 64 * 8 * 2);    // 64 frags
    _Float16* w2t = (_Float16*)alloc((size_t)128 * 64 * 8 * 2);   // 128 frags
    _Float16* wct = (_Float16*)alloc((size_t)64 * 64 * 8 * 2);    // 64 frags
    (void)ws_size; (void)in_sizes; (void)n_in; (void)out_size;

    int gn = (NNODES + 255) / 256;
    int ge = (NEDGES + 255) / 256;
    int gt = (NTOT + 255) / 256;

    // CSR build (same graph for both layers)
    hipMemsetAsync(counts, 0, (size_t)NNODES * 4, stream);
    k_count<<<ge, 256, 0, stream>>>(ei, counts);
    k_scan1<<<gn, 256, 0, stream>>>(counts, row_ptr, bsums);
    k_scan2<<<1, 256, 0, stream>>>(bsums, boff, gn);
    k_scan3<<<gn, 256, 0, stream>>>(row_ptr, boff, cursor);
    k_scatter<<<gt, 256, 0, stream>>>(ei, cursor, esrc);

    // weight prep (fragment pack, all three)
    k_prep_all<<<64, 256, 0, stream>>>(W1, W2, Wc, w1t, w2t, wct);

    dim3 gHid(HHD / TBN, (NNODES + TBM - 1) / TBM);   // (2, 782)
    dim3 gCls(1, (NNODES + TBM - 1) / TBM);           // (1, 782)
    int gagg = NNODES / 8;            // 8 nodes/block (2 per wave)

    // layer 1 (GEMM + fused alpha)
    k_mfma_gemm<float, 128, 0><<<gHid, 256, 0, stream>>>(
        x, w1t, xh_h, nullptr, nullptr, a1s, a1d, as_, ad_, NNODES, HHD);
    k_agg<<<gagg, 256, 0, stream>>>(xh_h, as_, ad_, row_ptr, esrc, b1, hbuf_h);

    // layer 2 (GEMM + fused alpha)
    k_mfma_gemm<_Float16, 256, 0><<<gHid, 256, 0, stream>>>(
        hbuf_h, w2t, xh_h, nullptr, nullptr, a2s, a2d, as_, ad_, NNODES, HHD);
    k_agg<<<gagg, 256, 0, stream>>>(xh_h, as_, ad_, row_ptr, esrc, b2, hbuf_h);

    // classifier
    k_mfma_gemm<_Float16, 256, 1><<<gCls, 256, 0, stream>>>(
        hbuf_h, wct, nullptr, out, bc, nullptr, nullptr, nullptr, nullptr,
        NNODES, NCLS);
}

// Round 17
// 316.256 us; speedup vs baseline: 1.0205x; 1.0205x over previous
//
#include <hip/hip_runtime.h>
#include <math.h>

#define NNODES 50000
#define NEDGES 800000
#define NTOT   850000   // edges + self-loops
#define NHEAD  8
#define HDIM   32
#define HHD    256      // NHEAD*HDIM
#define NCLS   40
#define NEG_SLOPE 0.2f

typedef _Float16 half4 __attribute__((ext_vector_type(4)));
typedef _Float16 half8 __attribute__((ext_vector_type(8)));
typedef float f32x16 __attribute__((ext_vector_type(16)));
typedef unsigned short u16;

// ---------------- CSR build ----------------

__global__ void k_init_counts(int* __restrict__ counts) {
    int i = blockIdx.x * 256 + threadIdx.x;
    if (i < NNODES) counts[i] = 1;   // self-loop
}

__global__ void k_count(const int* __restrict__ ei, int* __restrict__ counts) {
    int i = blockIdx.x * 256 + threadIdx.x;
    if (i < NEDGES) atomicAdd(&counts[ei[NEDGES + i]], 1);  // dst row
}

__global__ __launch_bounds__(256) void k_scan1(const int* __restrict__ counts,
                                               int* __restrict__ partial,
                                               int* __restrict__ bsums) {
    __shared__ int lds[256];
    int t = threadIdx.x;
    int i = blockIdx.x * 256 + t;
    int v = (i < NNODES) ? counts[i] : 0;
    lds[t] = v;
    __syncthreads();
    for (int off = 1; off < 256; off <<= 1) {
        int add = (t >= off) ? lds[t - off] : 0;
        __syncthreads();
        lds[t] += add;
        __syncthreads();
    }
    if (i < NNODES) partial[i] = lds[t] - v;   // exclusive within block
    if (t == 255) bsums[blockIdx.x] = lds[255];
}

__global__ __launch_bounds__(256) void k_scan2(const int* __restrict__ bsums,
                                               int* __restrict__ boff, int nb) {
    __shared__ int lds[256];
    int t = threadIdx.x;
    int v = (t < nb) ? bsums[t] : 0;
    lds[t] = v;
    __syncthreads();
    for (int off = 1; off < 256; off <<= 1) {
        int add = (t >= off) ? lds[t - off] : 0;
        __syncthreads();
        lds[t] += add;
        __syncthreads();
    }
    if (t < nb) boff[t] = lds[t] - v;
}

__global__ void k_scan3(int* __restrict__ row_ptr, const int* __restrict__ boff,
                        int* __restrict__ cursor) {
    int i = blockIdx.x * 256 + threadIdx.x;
    if (i < NNODES) {
        int r = row_ptr[i] + boff[blockIdx.x];
        row_ptr[i] = r;
        cursor[i] = r;
    }
    if (i == 0) row_ptr[NNODES] = NTOT;
}

// fused: regular edges + self-loops
__global__ void k_scatter(const int* __restrict__ ei, int* __restrict__ cursor,
                          int* __restrict__ esrc) {
    int i = blockIdx.x * 256 + threadIdx.x;
    if (i < NEDGES) {
        int s = ei[i];
        int d = ei[NEDGES + i];
        int pos = atomicAdd(&cursor[d], 1);
        esrc[pos] = s;
    } else if (i < NTOT) {
        int n = i - NEDGES;
        int pos = atomicAdd(&cursor[n], 1);
        esrc[pos] = n;
    }
}

// ---------------- weight prep: all three weights, MFMA fragment layout -----
// frag f=(fn,fk); lane l holds 8 halves of col n=fn*32+(l&31),
// rows k=fk*16+((l>>5)<<3)+j. 1 KB contiguous per frag.
__global__ void k_prep_all(const float* __restrict__ W1, const float* __restrict__ W2,
                           const float* __restrict__ Wc,
                           _Float16* __restrict__ w1t, _Float16* __restrict__ w2t,
                           _Float16* __restrict__ wct) {
    int gid = blockIdx.x * 256 + threadIdx.x;   // 256 frags x 64 lanes
    if (gid >= 256 * 64) return;
    int frag = gid >> 6, l = gid & 63;
    const float* W; _Float16* Wt; int K, Nc, fkn, fbase;
    if (frag < 64)       { W = W1; Wt = w1t; K = 128; Nc = 256; fkn = 8;  fbase = 0; }
    else if (frag < 192) { W = W2; Wt = w2t; K = 256; Nc = 256; fkn = 16; fbase = 64; }
    else                 { W = Wc; Wt = wct; K = 256; Nc = 40;  fkn = 16; fbase = 192; }
    int f = frag - fbase;
    int fn = f / fkn, fk = f - fn * fkn;
    int n = fn * 32 + (l & 31);
    int k = fk * 16 + ((l >> 5) << 3);
    half8 v;
    #pragma unroll
    for (int j = 0; j < 8; ++j)
        v[j] = (n < Nc) ? (_Float16)W[(size_t)(k + j) * Nc + n] : (_Float16)0.f;
    *reinterpret_cast<half8*>(Wt + ((size_t)f * 64 + l) * 8) = v;
}

// ---------------- MFMA f16 GEMM: one-shot full-K staging (COALESCED) -------
// A-tile (64 x K fp16) staged once into LDS with wave-contiguous loads
// (iteration = 1 KB contiguous per wave), then all K/16 MFMA steps run
// barrier-free. MODE 0: fp16 C via Ct union + alpha epilogue.
// MODE 1: direct fp32 + bias, cols < NCLS.
#define TBM 64
#define TBN 128
#define LDCT 132   // Ct row stride in halves

template <typename AT, int K, int MODE>
__global__ __launch_bounds__(256) void k_mfma_gemm(
    const AT* __restrict__ A,
    const _Float16* __restrict__ Wt,   // fragment-packed
    _Float16* __restrict__ Ch,
    float* __restrict__ Cf,
    const float* __restrict__ bias,
    const float* __restrict__ a_src,   // [8][32] (MODE 0)
    const float* __restrict__ a_dst,
    float* __restrict__ alpha_s,       // [N][8]
    float* __restrict__ alpha_d,
    int M, int ldc)
{
    constexpr bool A_IS_F32 = sizeof(AT) == 4;
    constexpr int APADK = K + 2;   // odd dword row stride -> conflict-free b128
    constexpr int A_ELEMS = TBM * APADK;
    constexpr int CT_ELEMS = (MODE == 0) ? TBM * LDCT : 0;
    constexpr int SMEM_ELEMS = (A_ELEMS > CT_ELEMS) ? A_ELEMS : CT_ELEMS;
    __shared__ _Float16 smem[SMEM_ELEMS];
    int t = threadIdx.x;
    int lane = t & 63;
    int wid = t >> 6;
    int wr = wid >> 1, wc = wid & 1;            // 2x2 wave grid; wave = 32r x 64c
    int rowBase = blockIdx.y * TBM;
    int colBase = blockIdx.x * TBN;

    constexpr int FKN = K >> 4;       // frags per n-tile row
    constexpr int CPR = K / 8;        // half8-chunks per row
    size_t bbase[2];
    #pragma unroll
    for (int ct = 0; ct < 2; ++ct) {
        int fn = blockIdx.x * 4 + wc * 2 + ct;
        bbase[ct] = ((size_t)fn * FKN) * 512 + (size_t)lane * 8;
    }

    f32x16 acc[2];
    #pragma unroll
    for (int j = 0; j < 2; ++j)
        #pragma unroll
        for (int r = 0; r < 16; ++r) acc[j][r] = 0.f;

    // ---- one-shot coalesced A staging ----
    // chunk idx = c*256 + t; row = idx/CPR, col = (idx%CPR)*8.
    // consecutive threads -> consecutive 16 B chunks -> wave = 1 KB contiguous.
    #pragma unroll
    for (int c = 0; c < K / 32; ++c) {
        int idx = c * 256 + t;
        int row = idx / CPR;
        int col = (idx % CPR) * 8;
        int grow = rowBase + row;
        bool ok = grow < M;
        half8 hv;
        if constexpr (A_IS_F32) {
            float4 v0 = {0.f, 0.f, 0.f, 0.f}, v1 = {0.f, 0.f, 0.f, 0.f};
            if (ok) {
                const float* ap = (const float*)A + (size_t)grow * K + col;
                v0 = *reinterpret_cast<const float4*>(ap);
                v1 = *reinterpret_cast<const float4*>(ap + 4);
            }
            hv[0] = (_Float16)v0.x; hv[1] = (_Float16)v0.y;
            hv[2] = (_Float16)v0.z; hv[3] = (_Float16)v0.w;
            hv[4] = (_Float16)v1.x; hv[5] = (_Float16)v1.y;
            hv[6] = (_Float16)v1.z; hv[7] = (_Float16)v1.w;
        } else {
            hv = ok ? *reinterpret_cast<const half8*>((const _Float16*)A + (size_t)grow * K + col)
                    : half8{0, 0, 0, 0, 0, 0, 0, 0};
        }
        *reinterpret_cast<half8*>(&smem[row * APADK + col]) = hv;
    }
    __syncthreads();

    // ---- barrier-free MFMA loop over all K ----
    #pragma unroll
    for (int fk = 0; fk < FKN; ++fk) {
        int kfo = fk * 16 + (lane >> 5) * 8;
        half8 ah = *reinterpret_cast<const half8*>(
            &smem[(wr * 32 + (lane & 31)) * APADK + kfo]);
        #pragma unroll
        for (int ct = 0; ct < 2; ++ct) {
            half8 bh = *reinterpret_cast<const half8*>(
                Wt + bbase[ct] + (size_t)fk * 512);
            acc[ct] = __builtin_amdgcn_mfma_f32_32x32x16_f16(ah, bh, acc[ct], 0, 0, 0);
        }
    }
    __syncthreads();
    // smem (A) dead -> reused as Ct (MODE 0)

    if constexpr (MODE == 0) {
        // acc -> Ct (scalar LDS stores; C-layout transpose)
        #pragma unroll
        for (int ct = 0; ct < 2; ++ct) {
            int lcol = wc * 64 + ct * 32 + (lane & 31);
            #pragma unroll
            for (int r = 0; r < 16; ++r) {
                int lrow = wr * 32 + (r & 3) + 8 * (r >> 2) + 4 * (lane >> 5);
                smem[lrow * LDCT + lcol] = (_Float16)acc[ct][r];
            }
        }
        __syncthreads();
        // vectorized C write: 64 rows x 16 col-chunks (half8) = 4 passes
        #pragma unroll
        for (int pass = 0; pass < 4; ++pass) {
            int idx = t + pass * 256;
            int lrow = idx >> 4;
            int cchunk = (idx & 15) * 8;
            int grow = rowBase + lrow;
            if (grow < M) {
                half8 v = *reinterpret_cast<const half8*>(&smem[lrow * LDCT + cchunk]);
                *reinterpret_cast<half8*>(Ch + (size_t)grow * ldc + colBase + cchunk) = v;
            }
        }
        // alpha epilogue: 64 rows x 4 heads = 256 pairs, 1 per thread
        {
            int lrow = t >> 2, hoff = t & 3;
            int grow = rowBase + lrow;
            if (grow < M) {
                int h = blockIdx.x * 4 + hoff;
                const float* as4 = a_src + h * HDIM;
                const float* ad4 = a_dst + h * HDIM;
                float ss = 0.f, sd = 0.f;
                #pragma unroll
                for (int j = 0; j < HDIM; ++j) {
                    float v = (float)smem[lrow * LDCT + hoff * 32 + j];
                    ss += v * as4[j];
                    sd += v * ad4[j];
                }
                alpha_s[grow * NHEAD + h] = ss;
                alpha_d[grow * NHEAD + h] = sd;
            }
        }
    } else {
        // classifier: direct fp32 + bias, cols < NCLS
        #pragma unroll
        for (int ct = 0; ct < 2; ++ct) {
            int col = colBase + wc * 64 + ct * 32 + (lane & 31);
            #pragma unroll
            for (int r = 0; r < 16; ++r) {
                int row = rowBase + wr * 32 + (r & 3) + 8 * (r >> 2) + 4 * (lane >> 5);
                if (row < M && col < NCLS)
                    Cf[(size_t)row * ldc + col] = acc[ct][r] + bias[col];
            }
        }
    }
}

// ---------------- GAT aggregation: fused single-pass softmax + gather ------
// 2 nodes per wave; lane l in [0,32) covers dims [8l, 8l+8) via one half8.
// No max-subtraction: e is a small-scale dot (|e| << 80), exp cannot overflow.
// Manual 4-way unroll for memory-level parallelism (4 gathers in flight).
__global__ __launch_bounds__(256) void k_agg(const _Float16* __restrict__ xh,
                                             const float* __restrict__ alpha_s,
                                             const float* __restrict__ alpha_d,
                                             const int* __restrict__ row_ptr,
                                             const int* __restrict__ esrc,
                                             const float* __restrict__ bias,
                                             _Float16* __restrict__ out) {
    int wave = blockIdx.x * 4 + (threadIdx.x >> 6);
    int node = wave * 2 + ((threadIdx.x & 63) >> 5);
    if (node >= NNODES) return;
    int l = threadIdx.x & 31;        // dim chunk [8l, 8l+8)
    int h = l >> 2;                  // head of this chunk
    int beg = row_ptr[node], end = row_ptr[node + 1];
    float ad = alpha_d[node * NHEAD + h];
    float acc[8] = {};
    float ssum = 0.f;
    int i = beg;
    for (; i + 3 < end; i += 4) {
        int s0 = esrc[i], s1 = esrc[i + 1], s2 = esrc[i + 2], s3 = esrc[i + 3];
        float e0 = alpha_s[s0 * NHEAD + h] + ad;
        float e1 = alpha_s[s1 * NHEAD + h] + ad;
        float e2 = alpha_s[s2 * NHEAD + h] + ad;
        float e3 = alpha_s[s3 * NHEAD + h] + ad;
        half8 v0 = *reinterpret_cast<const half8*>(xh + (size_t)s0 * HHD + l * 8);
        half8 v1 = *reinterpret_cast<const half8*>(xh + (size_t)s1 * HHD + l * 8);
        half8 v2 = *reinterpret_cast<const half8*>(xh + (size_t)s2 * HHD + l * 8);
        half8 v3 = *reinterpret_cast<const half8*>(xh + (size_t)s3 * HHD + l * 8);
        e0 = (e0 > 0.f) ? e0 : NEG_SLOPE * e0;
        e1 = (e1 > 0.f) ? e1 : NEG_SLOPE * e1;
        e2 = (e2 > 0.f) ? e2 : NEG_SLOPE * e2;
        e3 = (e3 > 0.f) ? e3 : NEG_SLOPE * e3;
        float p0 = __expf(e0), p1 = __expf(e1), p2 = __expf(e2), p3 = __expf(e3);
        ssum += (p0 + p1) + (p2 + p3);
        #pragma unroll
        for (int d = 0; d < 8; ++d)
            acc[d] += p0 * (float)v0[d] + p1 * (float)v1[d] +
                      p2 * (float)v2[d] + p3 * (float)v3[d];
    }
    for (; i < end; ++i) {
        int s0 = esrc[i];
        float e0 = alpha_s[s0 * NHEAD + h] + ad;
        half8 v0 = *reinterpret_cast<const half8*>(xh + (size_t)s0 * HHD + l * 8);
        e0 = (e0 > 0.f) ? e0 : NEG_SLOPE * e0;
        float p0 = __expf(e0);
        ssum += p0;
        #pragma unroll
        for (int d = 0; d < 8; ++d)
            acc[d] += p0 * (float)v0[d];
    }
    float inv = 1.f / ssum;
    float4 b0 = *reinterpret_cast<const float4*>(bias + l * 8);
    float4 b1 = *reinterpret_cast<const float4*>(bias + l * 8 + 4);
    float bb[8] = {b0.x, b0.y, b0.z, b0.w, b1.x, b1.y, b1.z, b1.w};
    half8 r;
    #pragma unroll
    for (int d = 0; d < 8; ++d)
        r[d] = (_Float16)fmaxf(acc[d] * inv + bb[d], 0.f);
    *reinterpret_cast<half8*>(out + (size_t)node * HHD + l * 8) = r;
}

// ---------------- launch ----------------

extern "C" void kernel_launch(void* const* d_in, const int* in_sizes, int n_in,
                              void* d_out, int out_size, void* d_ws, size_t ws_size,
                              hipStream_t stream) {
    const float* x   = (const float*)d_in[0];
    const int*   ei  = (const int*)  d_in[1];
    const float* W1  = (const float*)d_in[2];
    const float* a1s = (const float*)d_in[3];
    const float* a1d = (const float*)d_in[4];
    const float* b1  = (const float*)d_in[5];
    const float* W2  = (const float*)d_in[6];
    const float* a2s = (const float*)d_in[7];
    const float* a2d = (const float*)d_in[8];
    const float* b2  = (const float*)d_in[9];
    const float* Wc  = (const float*)d_in[10];
    const float* bc  = (const float*)d_in[11];
    float* out = (float*)d_out;

    char* ws = (char*)d_ws;
    size_t off = 0;
    auto alloc = [&](size_t bytes) -> void* {
        void* p = ws + off;
        off += (bytes + 255) & ~(size_t)255;
        return p;
    };
    _Float16* xh_h   = (_Float16*)alloc((size_t)NNODES * HHD * 2);
    _Float16* hbuf_h = (_Float16*)alloc((size_t)NNODES * HHD * 2);
    float* as_   = (float*)alloc((size_t)NNODES * NHEAD * 4);
    float* ad_   = (float*)alloc((size_t)NNODES * NHEAD * 4);
    int* counts  = (int*)alloc((size_t)NNODES * 4);
    int* row_ptr = (int*)alloc((size_t)(NNODES + 1) * 4);
    int* cursor  = (int*)alloc((size_t)NNODES * 4);
    int* esrc    = (int*)alloc((size_t)NTOT * 4);
    int* bsums   = (int*)alloc(256 * 4);
    int* boff    = (int*)alloc(256 * 4);
    _Float16* w1t = (_Float16*)alloc((size_t)64 * 64 * 8 * 2);    // 64 frags
    _Float16* w2t = (_Float16*)alloc((size_t)128 * 64 * 8 * 2);   // 128 frags
    _Float16* wct = (_Float16*)alloc((size_t)64 * 64 * 8 * 2);    // 64 frags
    (void)ws_size; (void)in_sizes; (void)n_in; (void)out_size;

    int gn = (NNODES + 255) / 256;
    int ge = (NEDGES + 255) / 256;
    int gt = (NTOT + 255) / 256;

    // CSR build (same graph for both layers)
    k_init_counts<<<gn, 256, 0, stream>>>(counts);
    k_count<<<ge, 256, 0, stream>>>(ei, counts);
    k_scan1<<<gn, 256, 0, stream>>>(counts, row_ptr, bsums);
    k_scan2<<<1, 256, 0, stream>>>(bsums, boff, gn);
    k_scan3<<<gn, 256, 0, stream>>>(row_ptr, boff, cursor);
    k_scatter<<<gt, 256, 0, stream>>>(ei, cursor, esrc);

    // weight prep (fragment pack, all three)
    k_prep_all<<<64, 256, 0, stream>>>(W1, W2, Wc, w1t, w2t, wct);

    dim3 gHid(HHD / TBN, (NNODES + TBM - 1) / TBM);   // (2, 782)
    dim3 gCls(1, (NNODES + TBM - 1) / TBM);           // (1, 782)
    int gagg = NNODES / 8;            // 8 nodes/block (2 per wave)

    // layer 1 (GEMM + fused alpha)
    k_mfma_gemm<float, 128, 0><<<gHid, 256, 0, stream>>>(
        x, w1t, xh_h, nullptr, nullptr, a1s, a1d, as_, ad_, NNODES, HHD);
    k_agg<<<gagg, 256, 0, stream>>>(xh_h, as_, ad_, row_ptr, esrc, b1, hbuf_h);

    // layer 2 (GEMM + fused alpha)
    k_mfma_gemm<_Float16, 256, 0><<<gHid, 256, 0, stream>>>(
        hbuf_h, w2t, xh_h, nullptr, nullptr, a2s, a2d, as_, ad_, NNODES, HHD);
    k_agg<<<gagg, 256, 0, stream>>>(xh_h, as_, ad_, row_ptr, esrc, b2, hbuf_h);

    // classifier
    k_mfma_gemm<_Float16, 256, 1><<<gCls, 256, 0, stream>>>(
        hbuf_h, wct, nullptr, out, bc, nullptr, nullptr, nullptr, nullptr,
        NNODES, NCLS);
}